// Round 15
// baseline (435.420 us; speedup 1.0000x reference)
//
#include <hip/hip_runtime.h>
#include <hip/hip_bf16.h>
#include <math.h>

#define B_   16
#define S_   512
#define D_   1024
#define H_   16
#define DK_  64
#define DFF_ 4096
#define NROW (B_ * S_)   // 8192
#define NEG_ (-1.0e9f)
#define SCQ_ 0.18033688011112042f   // 0.125 * log2(e): QK^T lands in log2 units

typedef __attribute__((ext_vector_type(8))) short short8v;   // 8 bf16 = 4 VGPRs
typedef __attribute__((ext_vector_type(4))) float f32x4;

__device__ __forceinline__ void load_lds16(const void* g, void* l) {
    __builtin_amdgcn_global_load_lds(
        reinterpret_cast<const __attribute__((address_space(1))) unsigned int*>(
            reinterpret_cast<uintptr_t>(g)),
        reinterpret_cast<__attribute__((address_space(3))) unsigned int*>(
            reinterpret_cast<uintptr_t>(l)),
        16, 0, 0);
}

__device__ __forceinline__ ushort f2bf_raw(float f) {
    __hip_bfloat16 h = __float2bfloat16(f);
    return *(ushort*)&h;
}

__device__ __forceinline__ float gelu_f(float v) {
    return 0.5f * v * (1.0f + erff(v * 0.70710678118654752f));
}

// ---------------------------------------------------------------------------
// preamble kernels (3 dispatches)
// ---------------------------------------------------------------------------
__global__ __launch_bounds__(256) void maskpack_k(
    const int* __restrict__ mask, unsigned long long* __restrict__ bits,
    unsigned int* __restrict__ scales) {
    if (blockIdx.x == 0 && threadIdx.x < 3) scales[threadIdx.x] = 0u;
    const int g = blockIdx.x * 4 + (threadIdx.x >> 6);
    const unsigned long long bm = __ballot(mask[(size_t)g * 64 + (threadIdx.x & 63)] != 0);
    if ((threadIdx.x & 63) == 0) bits[g] = bm;
}

__global__ __launch_bounds__(256) void maxabs3_k(
    const float* __restrict__ wq, const float* __restrict__ wk,
    const float* __restrict__ wv, unsigned int* __restrict__ out, int n) {
    const int wi = blockIdx.y;
    const float* w = wi == 0 ? wq : (wi == 1 ? wk : wv);
    float m = 0.f;
    for (int i = blockIdx.x * blockDim.x + threadIdx.x; i < n; i += gridDim.x * blockDim.x)
        m = fmaxf(m, fabsf(w[i]));
#pragma unroll
    for (int off = 1; off < 64; off <<= 1)
        m = fmaxf(m, __shfl_xor(m, off));
    __shared__ float red[4];
    const int wave = threadIdx.x >> 6;
    if ((threadIdx.x & 63) == 0) red[wave] = m;
    __syncthreads();
    if (threadIdx.x == 0) {
        m = fmaxf(fmaxf(red[0], red[1]), fmaxf(red[2], red[3]));
        atomicMax(out + wi, __float_as_uint(m));
    }
}

__global__ __launch_bounds__(256) void transq_all_k(
    const float* __restrict__ wq, const float* __restrict__ wk,
    const float* __restrict__ wv, const float* __restrict__ wo,
    const float* __restrict__ w1, const float* __restrict__ w2,
    const unsigned int* __restrict__ scales,
    __hip_bfloat16* __restrict__ wcat,
    __hip_bfloat16* __restrict__ wot,
    __hip_bfloat16* __restrict__ w1t, __hip_bfloat16* __restrict__ w2t)
{
    const int bid = blockIdx.x;
    int wi, rem, nbn, K, N;
    if (bid < 4096)      { wi = bid >> 10; rem = bid & 1023; nbn = 32;  K = 1024; N = 1024; }
    else if (bid < 8192) { wi = 4; rem = bid - 4096;         nbn = 128; K = 1024; N = 4096; }
    else                 { wi = 5; rem = bid - 8192;         nbn = 32;  K = 4096; N = 1024; }
    const float* W = wi == 0 ? wq : wi == 1 ? wk : wi == 2 ? wv : wi == 3 ? wo : wi == 4 ? w1 : w2;
    __hip_bfloat16* Wt = wi < 3 ? wcat + (size_t)wi * 1024 * 1024
                       : wi == 3 ? wot : wi == 4 ? w1t : w2t;
    const int n0 = (rem % nbn) * 32, k0 = (rem / nbn) * 32;

    __shared__ float t[32][33];
    const int tx = threadIdx.x, ty = threadIdx.y;
    float scale = 1.0f;
    const bool doq = wi < 3;
    if (doq) scale = __uint_as_float(scales[wi]) * (1.0f / 127.0f);
#pragma unroll
    for (int i = 0; i < 4; ++i) {
        float v = W[(size_t)(k0 + ty + 8 * i) * N + n0 + tx];
        if (doq) v = rintf(v / scale) * scale;
        t[ty + 8 * i][tx] = v;
    }
    __syncthreads();
#pragma unroll
    for (int i = 0; i < 4; ++i)
        Wt[(size_t)(n0 + ty + 8 * i) * K + k0 + tx] = __float2bfloat16(t[tx][ty + 8 * i]);
}

// ---------------------------------------------------------------------------
// layer norm fp32 -> bf16
// ---------------------------------------------------------------------------
__global__ __launch_bounds__(256) void ln_bf16_k(
    const float* __restrict__ x, const float* __restrict__ g,
    const float* __restrict__ b, __hip_bfloat16* __restrict__ y)
{
    const int row = blockIdx.x;
    const int tid = threadIdx.x;
    const float4 v = *(const float4*)&x[(size_t)row * D_ + tid * 4];

    float s = v.x + v.y + v.z + v.w;
#pragma unroll
    for (int off = 1; off < 64; off <<= 1) s += __shfl_xor(s, off);
    __shared__ float red[8];
    const int wave = tid >> 6, lane = tid & 63;
    if (lane == 0) red[wave] = s;
    __syncthreads();
    s = red[0] + red[1] + red[2] + red[3];
    const float mu = s * (1.0f / (float)D_);

    const float d0 = v.x - mu, d1 = v.y - mu, d2 = v.z - mu, d3 = v.w - mu;
    float sq = d0 * d0 + d1 * d1 + d2 * d2 + d3 * d3;
#pragma unroll
    for (int off = 1; off < 64; off <<= 1) sq += __shfl_xor(sq, off);
    if (lane == 0) red[4 + wave] = sq;
    __syncthreads();
    sq = red[4] + red[5] + red[6] + red[7];
    const float rs = 1.0f / sqrtf(sq * (1.0f / (float)D_) + 1e-5f);

    const float4 gv = *(const float4*)&g[tid * 4];
    const float4 bv = *(const float4*)&b[tid * 4];
    union { ushort4 u4; ushort u[4]; } cv;
    cv.u[0] = f2bf_raw(d0 * rs * gv.x + bv.x);
    cv.u[1] = f2bf_raw(d1 * rs * gv.y + bv.y);
    cv.u[2] = f2bf_raw(d2 * rs * gv.z + bv.z);
    cv.u[3] = f2bf_raw(d3 * rs * gv.w + bv.w);
    *(ushort4*)&y[(size_t)row * D_ + tid * 4] = cv.u4;
}

// ---------------------------------------------------------------------------
// 256-wide 8-phase MFMA GEMM (round-11 exact: best measured config).
// ---------------------------------------------------------------------------
template <int BNT, int EPI>
__global__ __launch_bounds__(512, 2) void gemm256(
    const __hip_bfloat16* __restrict__ A, const __hip_bfloat16* __restrict__ Bt,
    const float* __restrict__ bias, const float* __restrict__ bias2,
    const float* __restrict__ bias3, const float* __restrict__ res,
    void* __restrict__ C, void* __restrict__ C2, void* __restrict__ C3,
    int M, int N, int K)
{
    constexpr int BN   = BNT * 64;
    constexpr int ABYT = 256 * 128;
    constexpr int BBYT = BN * 128;
    constexpr int BUF  = ABYT + BBYT;
    constexpr int SB   = BNT / 2;
    __shared__ __align__(16) char smem[2 * BUF];

    const int tid = threadIdx.x;
    const int w = tid >> 6, lane = tid & 63;
    const int llo = lane & 15, lhi = lane >> 4;
    const int wr = w >> 2, wc = w & 3;

    const int nwg = gridDim.x;
    const int bid = blockIdx.x;
    const int swz = (bid & 7) * (nwg >> 3) + (bid >> 3);
    const int nby = M >> 8;
    const int by = swz % nby, bx = swz / nby;
    const int row0 = by * 256, col0 = bx * BN;

    const int cko0 = ((lhi) ^ (llo & 7)) * 16;
    const int cko1 = ((4 + lhi) ^ (llo & 7)) * 16;

    const int l3 = lane >> 3;
    const int klog8 = ((lane & 7) ^ l3) * 8;
    const int rA_base = ((w >> 1) & 3) * 16 + (w & 1) * 8 + l3;
    const int rB_ws = w * 8 + l3;

    const __hip_bfloat16* Asrc[2][2];
#pragma unroll
    for (int h = 0; h < 2; ++h)
#pragma unroll
        for (int s = 0; s < 2; ++s)
            Asrc[h][s] = A + (size_t)(row0 + s * 128 + h * 64 + rA_base) * K + klog8;
    const __hip_bfloat16* Bsrc[2][2];
#pragma unroll
    for (int h = 0; h < 2; ++h)
#pragma unroll
        for (int s = 0; s < 2; ++s)
            Bsrc[h][s] = Bt + (size_t)(col0 + h * (BN / 2) + (SB == 2 ? s * 64 : 0) + rB_ws) * K + klog8;

#define STAGE_A(bufv, hh, tt) do {                                                            \
    load_lds16(Asrc[hh][0] + (size_t)(tt) * 64, smem + (bufv) * BUF + (hh) * 16384 + w * 1024);        \
    load_lds16(Asrc[hh][1] + (size_t)(tt) * 64, smem + (bufv) * BUF + (hh) * 16384 + 8192 + w * 1024); \
} while (0)
#define STAGE_B(bufv, hh, tt) do {                                                                     \
    load_lds16(Bsrc[hh][0] + (size_t)(tt) * 64, smem + (bufv) * BUF + ABYT + (hh) * (BBYT / 2) + w * 1024); \
    if (SB == 2)                                                                                       \
        load_lds16(Bsrc[hh][1] + (size_t)(tt) * 64, smem + (bufv) * BUF + ABYT + (hh) * (BBYT / 2) + 8192 + w * 1024); \
} while (0)

    f32x4 acc[8][BNT] = {};
    const int NT = K >> 6;

    STAGE_B(0, 0, 0); STAGE_B(0, 1, 0); STAGE_A(0, 0, 0); STAGE_A(0, 1, 0);
    asm volatile("s_waitcnt vmcnt(0)");
    __builtin_amdgcn_s_barrier();

    short8v bfr[BNT][2];
    for (int t = 0; t < NT; ++t) {
        const int buf = t & 1;
        const bool more = (t + 1) < NT;
        char* const base = smem + buf * BUF;
#pragma unroll
        for (int ph = 0; ph < 4; ++ph) {
            if (ph == 0) {
#pragma unroll
                for (int n = 0; n < BNT; ++n) {
                    const int brow = wc * (BNT * 16) + n * 16 + llo;
                    bfr[n][0] = *(const short8v*)(base + ABYT + brow * 128 + cko0);
                    bfr[n][1] = *(const short8v*)(base + ABYT + brow * 128 + cko1);
                }
            }
            const int mf0 = ph * 2, mf1 = ph * 2 + 1;
            const int slot0 = (mf0 >> 2) * 128 + wr * 64 + (mf0 & 3) * 16 + llo;
            const int slot1 = (mf1 >> 2) * 128 + wr * 64 + (mf1 & 3) * 16 + llo;
            const short8v a0k0 = *(const short8v*)(base + slot0 * 128 + cko0);
            const short8v a0k1 = *(const short8v*)(base + slot0 * 128 + cko1);
            const short8v a1k0 = *(const short8v*)(base + slot1 * 128 + cko0);
            const short8v a1k1 = *(const short8v*)(base + slot1 * 128 + cko1);
            if (more) {
                if (ph == 0) { STAGE_B(buf ^ 1, 0, t + 1); STAGE_B(buf ^ 1, 1, t + 1); }
                else if (ph == 1) { STAGE_A(buf ^ 1, 0, t + 1); STAGE_A(buf ^ 1, 1, t + 1); }
            }
            __builtin_amdgcn_s_barrier();
            __builtin_amdgcn_s_setprio(1);
#pragma unroll
            for (int n = 0; n < BNT; ++n) {
                acc[mf0][n] = __builtin_amdgcn_mfma_f32_16x16x32_bf16(a0k0, bfr[n][0], acc[mf0][n], 0, 0, 0);
                acc[mf0][n] = __builtin_amdgcn_mfma_f32_16x16x32_bf16(a0k1, bfr[n][1], acc[mf0][n], 0, 0, 0);
                acc[mf1][n] = __builtin_amdgcn_mfma_f32_16x16x32_bf16(a1k0, bfr[n][0], acc[mf1][n], 0, 0, 0);
                acc[mf1][n] = __builtin_amdgcn_mfma_f32_16x16x32_bf16(a1k1, bfr[n][1], acc[mf1][n], 0, 0, 0);
            }
            __builtin_amdgcn_s_setprio(0);
            if (ph == 3) { asm volatile("s_waitcnt vmcnt(0)"); }
            __builtin_amdgcn_s_barrier();
        }
    }
#undef STAGE_A
#undef STAGE_B

    if (EPI == 3) {
#pragma unroll
        for (int n = 0; n < BNT; ++n) {
            const int col = col0 + wc * (BNT * 16) + n * 16 + llo;
            const int proj = col0 >> 10;
            const int lcol = col & 1023;
            const float bs = (proj == 0 ? bias : proj == 1 ? bias2 : bias3)[lcol];
#pragma unroll
            for (int mf = 0; mf < 8; ++mf) {
                const int rbase = row0 + wr * 128 + mf * 16 + lhi * 4;
                if (proj == 2) {
                    const int bb = rbase >> 9, srow = rbase & 511;
                    const int hh = lcol >> 6, dk = lcol & 63;
                    union { ushort4 u4; ushort u[4]; } pk;
#pragma unroll
                    for (int j = 0; j < 4; ++j) pk.u[j] = f2bf_raw(acc[mf][n][j] + bs);
                    *(ushort4*)&((ushort*)C3)[(((size_t)(bb * 16 + hh) * 64 + dk) << 9) + srow] = pk.u4;
                } else {
                    __hip_bfloat16* dst = proj == 0 ? (__hip_bfloat16*)C : (__hip_bfloat16*)C2;
                    const float sc = proj == 0 ? SCQ_ : 1.0f;
#pragma unroll
                    for (int j = 0; j < 4; ++j)
                        dst[(size_t)(rbase + j) * D_ + lcol] = __float2bfloat16((acc[mf][n][j] + bs) * sc);
                }
            }
        }
    } else {
        constexpr int WCOL = BNT * 16;
        constexpr int ESTR = WCOL + 4;
        float* const eslab = (float*)smem + w * (16 * ESTR);
        const int rr = lane >> 2;
        const int cq = lane & 3;
        const int c0 = cq * (BNT * 4);
        const int gcolb = col0 + wc * WCOL + c0;
#pragma unroll
        for (int mf = 0; mf < 8; ++mf) {
#pragma unroll
            for (int n = 0; n < BNT; ++n)
#pragma unroll
                for (int j = 0; j < 4; ++j)
                    eslab[(lhi * 4 + j) * ESTR + n * 16 + llo] = acc[mf][n][j];
            const int grow = row0 + wr * 128 + mf * 16 + rr;
            if (EPI == 1) {
                ushort tmp[BNT * 4];
#pragma unroll
                for (int i = 0; i < BNT; ++i) {
                    float4 v = *(float4*)&eslab[rr * ESTR + c0 + i * 4];
                    const float4 b4 = *(const float4*)&bias[gcolb + i * 4];
                    tmp[i * 4 + 0] = f2bf_raw(gelu_f(v.x + b4.x));
                    tmp[i * 4 + 1] = f2bf_raw(gelu_f(v.y + b4.y));
                    tmp[i * 4 + 2] = f2bf_raw(gelu_f(v.z + b4.z));
                    tmp[i * 4 + 3] = f2bf_raw(gelu_f(v.w + b4.w));
                }
                ushort* dst = (ushort*)C + (size_t)grow * N + gcolb;
#pragma unroll
                for (int i = 0; i < BNT / 2; ++i)
                    *(short8v*)(dst + i * 8) = *(short8v*)&tmp[i * 8];
            } else {
#pragma unroll
                for (int i = 0; i < BNT; ++i) {
                    float4 v = *(float4*)&eslab[rr * ESTR + c0 + i * 4];
                    const float4 b4 = *(const float4*)&bias[gcolb + i * 4];
                    const float4 r4 = *(const float4*)&res[(size_t)grow * N + gcolb + i * 4];
                    v.x += b4.x + r4.x;
                    v.y += b4.y + r4.y;
                    v.z += b4.z + r4.z;
                    v.w += b4.w + r4.w;
                    *(float4*)&((float*)C)[(size_t)grow * N + gcolb + i * 4] = v;
                }
            }
        }
    }
}

// ---------------------------------------------------------------------------
// MFMA flash attention (KVBLK=64 + T13 defer-max) with:
//  - mask u64 loads hoisted before QK^T (latency hides under MFMAs)
//  - T5 setprio around QK and PV MFMA clusters (attn-verified +4-7%)
//  - coalesced O-write via Qs LDS bounce (wave-private rows, no barrier)
// ---------------------------------------------------------------------------
__global__ __launch_bounds__(256) void attn_mfma_k(
    const __hip_bfloat16* __restrict__ q, const __hip_bfloat16* __restrict__ k,
    const __hip_bfloat16* __restrict__ vt, const unsigned long long* __restrict__ mbits,
    __hip_bfloat16* __restrict__ o)
{
    const int qt = blockIdx.x;
    const int bh = blockIdx.y;
    const int b = bh >> 4, h = bh & 15;

    __shared__ __align__(16) __hip_bfloat16 Qs[64 * 72];
    __shared__ __align__(16) __hip_bfloat16 Ks[64 * 72];
    __shared__ __align__(16) __hip_bfloat16 Vts[64 * 72];
    __shared__ __align__(16) __hip_bfloat16 Pt[64 * 72];

    const int tid = threadIdx.x;
    const int w = tid >> 6, l = tid & 63;
    const int llo = l & 15, lhi = l >> 4;
    const int srow = tid >> 2, schk = tid & 3;

    {
        const __hip_bfloat16* qg =
            q + (size_t)(b * S_ + qt * 64 + srow) * D_ + h * 64 + schk * 16;
        *(short8v*)&Qs[srow * 72 + schk * 16] = *(const short8v*)qg;
        *(short8v*)&Qs[srow * 72 + schk * 16 + 8] = *(const short8v*)(qg + 8);
    }

    const __hip_bfloat16* kptr = k + (size_t)(b * S_ + srow) * D_ + h * 64 + schk * 16;
    const __hip_bfloat16* vptr = vt + (((size_t)(b * 16 + h) * 64 + srow) << 9) + schk * 16;
    short8v kr0 = *(const short8v*)kptr;
    short8v kr1 = *(const short8v*)(kptr + 8);
    short8v vr0 = *(const short8v*)vptr;
    short8v vr1 = *(const short8v*)(vptr + 8);

    __syncthreads();

    const short8v qa0 = *(const short8v*)&Qs[(w * 16 + llo) * 72 + lhi * 8];
    const short8v qa1 = *(const short8v*)&Qs[(w * 16 + llo) * 72 + 32 + lhi * 8];

    const unsigned long long* mrow =
        mbits + (((size_t)(b * S_ + qt * 64 + w * 16 + lhi * 4)) << 3);

    f32x4 oacc[4] = {};
    float m_r[4] = {-INFINITY, -INFINITY, -INFINITY, -INFINITY};
    float l_r[4] = {0.f, 0.f, 0.f, 0.f};

    for (int kt = 0; kt < 8; ++kt) {
        *(short8v*)&Ks[srow * 72 + schk * 16] = kr0;
        *(short8v*)&Ks[srow * 72 + schk * 16 + 8] = kr1;
        *(short8v*)&Vts[srow * 72 + schk * 16] = vr0;
        *(short8v*)&Vts[srow * 72 + schk * 16 + 8] = vr1;
        __syncthreads();

        // hoisted mask loads: in flight during QK^T MFMAs
        unsigned long long mbj[4];
#pragma unroll
        for (int j = 0; j < 4; ++j) mbj[j] = mrow[j * 8 + kt];

        short8v nk0, nk1, nv0, nv1;
        if (kt < 7) {
            const __hip_bfloat16* kp = kptr + (size_t)(kt + 1) * (64 * D_);
            const __hip_bfloat16* vp = vptr + (kt + 1) * 64;
            nk0 = *(const short8v*)kp;
            nk1 = *(const short8v*)(kp + 8);
            nv0 = *(const short8v*)vp;
            nv1 = *(const short8v*)(vp + 8);
        }

        f32x4 sacc[4] = {};
        __builtin_amdgcn_s_setprio(1);
#pragma unroll
        for (int n = 0; n < 4; ++n)
            sacc[n] = __builtin_amdgcn_mfma_f32_16x16x32_bf16(
                qa0, *(const short8v*)&Ks[(n * 16 + llo) * 72 + lhi * 8], sacc[n], 0, 0, 0);
#pragma unroll
        for (int n = 0; n < 4; ++n)
            sacc[n] = __builtin_amdgcn_mfma_f32_16x16x32_bf16(
                qa1, *(const short8v*)&Ks[(n * 16 + llo) * 72 + 32 + lhi * 8], sacc[n], 0, 0, 0);
        __builtin_amdgcn_s_setprio(0);

#pragma unroll
        for (int j = 0; j < 4; ++j) {
            const unsigned long long mb = mbj[j];
            const float s0 = ((mb >> llo) & 1ull)        ? sacc[0][j] : NEG_;
            const float s1 = ((mb >> (llo + 16)) & 1ull) ? sacc[1][j] : NEG_;
            const float s2 = ((mb >> (llo + 32)) & 1ull) ? sacc[2][j] : NEG_;
            const float s3 = ((mb >> (llo + 48)) & 1ull) ? sacc[3][j] : NEG_;
            float pm = fmaxf(fmaxf(s0, s1), fmaxf(s2, s3));
            pm = fmaxf(pm, __shfl_xor(pm, 1));
            pm = fmaxf(pm, __shfl_xor(pm, 2));
            pm = fmaxf(pm, __shfl_xor(pm, 4));
            pm = fmaxf(pm, __shfl_xor(pm, 8));
            float alpha = 1.0f;
            if (!__all(pm <= m_r[j] + 8.0f)) {
                const float mnew = fmaxf(m_r[j], pm);
                alpha = exp2f(m_r[j] - mnew);
                m_r[j] = mnew;
#pragma unroll
                for (int df = 0; df < 4; ++df) oacc[df][j] *= alpha;
            }
            const float p0 = exp2f(s0 - m_r[j]);
            const float p1 = exp2f(s1 - m_r[j]);
            const float p2 = exp2f(s2 - m_r[j]);
            const float p3 = exp2f(s3 - m_r[j]);
            float rsum = p0 + p1 + p2 + p3;
            rsum += __shfl_xor(rsum, 1);
            rsum += __shfl_xor(rsum, 2);
            rsum += __shfl_xor(rsum, 4);
            rsum += __shfl_xor(rsum, 8);
            l_r[j] = l_r[j] * alpha + rsum;
            const int prow = (w * 16 + lhi * 4 + j) * 72;
            Pt[prow + llo]      = __float2bfloat16(p0);
            Pt[prow + llo + 16] = __float2bfloat16(p1);
            Pt[prow + llo + 32] = __float2bfloat16(p2);
            Pt[prow + llo + 48] = __float2bfloat16(p3);
        }

        __builtin_amdgcn_s_setprio(1);
#pragma unroll
        for (int ks = 0; ks < 2; ++ks) {
            const short8v pa = *(const short8v*)&Pt[(w * 16 + llo) * 72 + ks * 32 + lhi * 8];
#pragma unroll
            for (int df = 0; df < 4; ++df) {
                const short8v vb = *(const short8v*)&Vts[(df * 16 + llo) * 72 + ks * 32 + lhi * 8];
                oacc[df] = __builtin_amdgcn_mfma_f32_16x16x32_bf16(pa, vb, oacc[df], 0, 0, 0);
            }
        }
        __builtin_amdgcn_s_setprio(0);
        __syncthreads();

        if (kt < 7) { kr0 = nk0; kr1 = nk1; vr0 = nv0; vr1 = nv1; }
    }

    // coalesced O-write: bounce through Qs (wave-private rows -> no barrier;
    // same-wave ds_write->ds_read ordered by lgkmcnt, as the Pt path)
#pragma unroll
    for (int j = 0; j < 4; ++j) {
        const float inv = 1.0f / l_r[j];
        const int qrow = w * 16 + lhi * 4 + j;
#pragma unroll
        for (int df = 0; df < 4; ++df)
            Qs[qrow * 72 + df * 16 + llo] = __float2bfloat16(oacc[df][j] * inv);
    }
    {
        const int rr = w * 16 + (l >> 2);
        const int cc = (l & 3) * 16;
        __hip_bfloat16* orow =
            o + (size_t)(b * S_ + qt * 64 + rr) * D_ + h * 64 + cc;
        *(short8v*)orow = *(const short8v*)&Qs[rr * 72 + cc];
        *(short8v*)(orow + 8) = *(const short8v*)&Qs[rr * 72 + cc + 8];
    }
}

// ---------------------------------------------------------------------------
// launch (10 dispatches)
// ---------------------------------------------------------------------------
extern "C" void kernel_launch(void* const* d_in, const int* in_sizes, int n_in,
                              void* d_out, int out_size, void* d_ws, size_t ws_size,
                              hipStream_t stream)
{
    const float* x    = (const float*)d_in[0];
    const int*   mask = (const int*)d_in[1];
    const float* wq   = (const float*)d_in[2];
    const float* bq   = (const float*)d_in[3];
    const float* wk   = (const float*)d_in[4];
    const float* bk   = (const float*)d_in[5];
    const float* wv   = (const float*)d_in[6];
    const float* bv   = (const float*)d_in[7];
    const float* wo   = (const float*)d_in[8];
    const float* bo   = (const float*)d_in[9];
    const float* w1   = (const float*)d_in[10];
    const float* b1   = (const float*)d_in[11];
    const float* w2   = (const float*)d_in[12];
    const float* b2   = (const float*)d_in[13];
    const float* ln1g = (const float*)d_in[14];
    const float* ln1b = (const float*)d_in[15];
    const float* ln2g = (const float*)d_in[16];
    const float* ln2b = (const float*)d_in[17];
    float* out = (float*)d_out;
    char* ws = (char*)d_ws;

    const size_t MB = 1024 * 1024;
    __hip_bfloat16* hb    = (__hip_bfloat16*)(ws);
    __hip_bfloat16* qbh   = (__hip_bfloat16*)(ws + 16 * MB);
    __hip_bfloat16* kbh   = (__hip_bfloat16*)(ws + 32 * MB);
    __hip_bfloat16* vth   = (__hip_bfloat16*)(ws + 48 * MB);
    __hip_bfloat16* attnb = (__hip_bfloat16*)(ws + 64 * MB);
    __hip_bfloat16* ff1b  = (__hip_bfloat16*)(ws + 16 * MB);
    __hip_bfloat16* wcat  = (__hip_bfloat16*)(ws + 80 * MB);
    __hip_bfloat16* wot   = (__hip_bfloat16*)(ws + 86 * MB);
    __hip_bfloat16* w1t   = (__hip_bfloat16*)(ws + 88 * MB);
    __hip_bfloat16* w2t   = (__hip_bfloat16*)(ws + 96 * MB);
    unsigned int*   scales = (unsigned int*)(ws + 104 * MB);
    unsigned long long* mbits = (unsigned long long*)(ws + 105 * MB);

    maskpack_k<<<(B_ * S_ * (S_ / 64)) / 4, 256, 0, stream>>>(mask, mbits, scales);
    maxabs3_k<<<dim3(256, 3), 256, 0, stream>>>(wq, wk, wv, scales, D_ * D_);
    transq_all_k<<<12288, dim3(32, 8), 0, stream>>>(
        wq, wk, wv, wo, w1, w2, scales, wcat, wot, w1t, w2t);

    ln_bf16_k<<<NROW, 256, 0, stream>>>(x, ln1g, ln1b, hb);

    // fused QKV: N = 3072, BNT=2 -> grid 768 = exactly 3 blocks/CU
    gemm256<2, 3><<<(3 * D_ / 128) * (NROW / 256), 512, 0, stream>>>(
        hb, wcat, bq, bk, bv, nullptr, qbh, kbh, vth, NROW, 3 * D_, D_);

    attn_mfma_k<<<dim3(S_ / 64, B_ * H_), 256, 0, stream>>>(qbh, kbh, vth, mbits, attnb);

    // x2 = x + attn @ wo + bo -> out (fp32).  BNT=2 -> grid 256
    gemm256<2, 2><<<(D_ / 128) * (NROW / 256), 512, 0, stream>>>(
        attnb, wot, bo, nullptr, nullptr, x, out, nullptr, nullptr, NROW, D_, D_);

    ln_bf16_k<<<NROW, 256, 0, stream>>>(out, ln2g, ln2b, hb);

    // ff1 = gelu(h2 @ w1 + b1) -> bf16.  BNT=4 -> grid 512
    gemm256<4, 1><<<(DFF_ / 256) * (NROW / 256), 512, 0, stream>>>(
        hb, w1t, b1, nullptr, nullptr, nullptr, ff1b, nullptr, nullptr, NROW, DFF_, D_);

    // out = x2 + ff1 @ w2 + b2 (fp32, res==C aliasing is per-thread-safe)
    gemm256<2, 2><<<(D_ / 128) * (NROW / 256), 512, 0, stream>>>(
        ff1b, w2t, b2, nullptr, nullptr, out, out, nullptr, nullptr, NROW, D_, DFF_);
}

// Round 16
// 420.260 us; speedup vs baseline: 1.0361x; 1.0361x over previous
//
#include <hip/hip_runtime.h>
#include <hip/hip_bf16.h>
#include <math.h>

#define B_   16
#define S_   512
#define D_   1024
#define H_   16
#define DK_  64
#define DFF_ 4096
#define NROW (B_ * S_)   // 8192
#define NEG_ (-1.0e9f)
#define SCQ_ 0.18033688011112042f   // 0.125 * log2(e): QK^T lands in log2 units

typedef __attribute__((ext_vector_type(8))) short short8v;   // 8 bf16 = 4 VGPRs
typedef __attribute__((ext_vector_type(4))) float f32x4;

__device__ __forceinline__ void load_lds16(const void* g, void* l) {
    __builtin_amdgcn_global_load_lds(
        reinterpret_cast<const __attribute__((address_space(1))) unsigned int*>(
            reinterpret_cast<uintptr_t>(g)),
        reinterpret_cast<__attribute__((address_space(3))) unsigned int*>(
            reinterpret_cast<uintptr_t>(l)),
        16, 0, 0);
}

__device__ __forceinline__ ushort f2bf_raw(float f) {
    __hip_bfloat16 h = __float2bfloat16(f);
    return *(ushort*)&h;
}

__device__ __forceinline__ float gelu_f(float v) {
    return 0.5f * v * (1.0f + erff(v * 0.70710678118654752f));
}

// ---------------------------------------------------------------------------
// preamble kernels (3 dispatches)
// ---------------------------------------------------------------------------
__global__ __launch_bounds__(256) void maskpack_k(
    const int* __restrict__ mask, unsigned long long* __restrict__ bits,
    unsigned int* __restrict__ scales) {
    if (blockIdx.x == 0 && threadIdx.x < 3) scales[threadIdx.x] = 0u;
    const int g = blockIdx.x * 4 + (threadIdx.x >> 6);
    const unsigned long long bm = __ballot(mask[(size_t)g * 64 + (threadIdx.x & 63)] != 0);
    if ((threadIdx.x & 63) == 0) bits[g] = bm;
}

__global__ __launch_bounds__(256) void maxabs3_k(
    const float* __restrict__ wq, const float* __restrict__ wk,
    const float* __restrict__ wv, unsigned int* __restrict__ out, int n) {
    const int wi = blockIdx.y;
    const float* w = wi == 0 ? wq : (wi == 1 ? wk : wv);
    float m = 0.f;
    for (int i = blockIdx.x * blockDim.x + threadIdx.x; i < n; i += gridDim.x * blockDim.x)
        m = fmaxf(m, fabsf(w[i]));
#pragma unroll
    for (int off = 1; off < 64; off <<= 1)
        m = fmaxf(m, __shfl_xor(m, off));
    __shared__ float red[4];
    const int wave = threadIdx.x >> 6;
    if ((threadIdx.x & 63) == 0) red[wave] = m;
    __syncthreads();
    if (threadIdx.x == 0) {
        m = fmaxf(fmaxf(red[0], red[1]), fmaxf(red[2], red[3]));
        atomicMax(out + wi, __float_as_uint(m));
    }
}

__global__ __launch_bounds__(256) void transq_all_k(
    const float* __restrict__ wq, const float* __restrict__ wk,
    const float* __restrict__ wv, const float* __restrict__ wo,
    const float* __restrict__ w1, const float* __restrict__ w2,
    const unsigned int* __restrict__ scales,
    __hip_bfloat16* __restrict__ wcat,
    __hip_bfloat16* __restrict__ wot,
    __hip_bfloat16* __restrict__ w1t, __hip_bfloat16* __restrict__ w2t)
{
    const int bid = blockIdx.x;
    int wi, rem, nbn, K, N;
    if (bid < 4096)      { wi = bid >> 10; rem = bid & 1023; nbn = 32;  K = 1024; N = 1024; }
    else if (bid < 8192) { wi = 4; rem = bid - 4096;         nbn = 128; K = 1024; N = 4096; }
    else                 { wi = 5; rem = bid - 8192;         nbn = 32;  K = 4096; N = 1024; }
    const float* W = wi == 0 ? wq : wi == 1 ? wk : wi == 2 ? wv : wi == 3 ? wo : wi == 4 ? w1 : w2;
    __hip_bfloat16* Wt = wi < 3 ? wcat + (size_t)wi * 1024 * 1024
                       : wi == 3 ? wot : wi == 4 ? w1t : w2t;
    const int n0 = (rem % nbn) * 32, k0 = (rem / nbn) * 32;

    __shared__ float t[32][33];
    const int tx = threadIdx.x, ty = threadIdx.y;
    float scale = 1.0f;
    const bool doq = wi < 3;
    if (doq) scale = __uint_as_float(scales[wi]) * (1.0f / 127.0f);
#pragma unroll
    for (int i = 0; i < 4; ++i) {
        float v = W[(size_t)(k0 + ty + 8 * i) * N + n0 + tx];
        if (doq) v = rintf(v / scale) * scale;
        t[ty + 8 * i][tx] = v;
    }
    __syncthreads();
#pragma unroll
    for (int i = 0; i < 4; ++i)
        Wt[(size_t)(n0 + ty + 8 * i) * K + k0 + tx] = __float2bfloat16(t[tx][ty + 8 * i]);
}

// ---------------------------------------------------------------------------
// layer norm fp32 -> bf16
// ---------------------------------------------------------------------------
__global__ __launch_bounds__(256) void ln_bf16_k(
    const float* __restrict__ x, const float* __restrict__ g,
    const float* __restrict__ b, __hip_bfloat16* __restrict__ y)
{
    const int row = blockIdx.x;
    const int tid = threadIdx.x;
    const float4 v = *(const float4*)&x[(size_t)row * D_ + tid * 4];

    float s = v.x + v.y + v.z + v.w;
#pragma unroll
    for (int off = 1; off < 64; off <<= 1) s += __shfl_xor(s, off);
    __shared__ float red[8];
    const int wave = tid >> 6, lane = tid & 63;
    if (lane == 0) red[wave] = s;
    __syncthreads();
    s = red[0] + red[1] + red[2] + red[3];
    const float mu = s * (1.0f / (float)D_);

    const float d0 = v.x - mu, d1 = v.y - mu, d2 = v.z - mu, d3 = v.w - mu;
    float sq = d0 * d0 + d1 * d1 + d2 * d2 + d3 * d3;
#pragma unroll
    for (int off = 1; off < 64; off <<= 1) sq += __shfl_xor(sq, off);
    if (lane == 0) red[4 + wave] = sq;
    __syncthreads();
    sq = red[4] + red[5] + red[6] + red[7];
    const float rs = 1.0f / sqrtf(sq * (1.0f / (float)D_) + 1e-5f);

    const float4 gv = *(const float4*)&g[tid * 4];
    const float4 bv = *(const float4*)&b[tid * 4];
    union { ushort4 u4; ushort u[4]; } cv;
    cv.u[0] = f2bf_raw(d0 * rs * gv.x + bv.x);
    cv.u[1] = f2bf_raw(d1 * rs * gv.y + bv.y);
    cv.u[2] = f2bf_raw(d2 * rs * gv.z + bv.z);
    cv.u[3] = f2bf_raw(d3 * rs * gv.w + bv.w);
    *(ushort4*)&y[(size_t)row * D_ + tid * 4] = cv.u4;
}

// ---------------------------------------------------------------------------
// 256-wide 8-phase MFMA GEMM (round-11 exact: best measured config).
// 512 threads = 8 waves (2M x 4N). BM=256, BN=BNT*64, BK=64. dbuf LDS.
// Both-sides swizzle (SQ_LDS_BANK_CONFLICT = 0). Deep prefetch: all of tile
// t+1 staged at ph0-1; single vmcnt(0) at ph3-end. Slab epilogue (ideal
// WRITE_SIZE). XCD-aware block swizzle.
// EPI: 1 = bias+gelu -> bf16 (FFN1)
//      2 = bias+residual -> fp32 (o-proj, FFN2)
//      3 = QKV split: proj0 -> C*SCQ_ bf16, proj1 -> C2 bf16, proj2 -> C3 vth
// ---------------------------------------------------------------------------
template <int BNT, int EPI>
__global__ __launch_bounds__(512, 2) void gemm256(
    const __hip_bfloat16* __restrict__ A, const __hip_bfloat16* __restrict__ Bt,
    const float* __restrict__ bias, const float* __restrict__ bias2,
    const float* __restrict__ bias3, const float* __restrict__ res,
    void* __restrict__ C, void* __restrict__ C2, void* __restrict__ C3,
    int M, int N, int K)
{
    constexpr int BN   = BNT * 64;
    constexpr int ABYT = 256 * 128;
    constexpr int BBYT = BN * 128;
    constexpr int BUF  = ABYT + BBYT;
    constexpr int SB   = BNT / 2;
    __shared__ __align__(16) char smem[2 * BUF];

    const int tid = threadIdx.x;
    const int w = tid >> 6, lane = tid & 63;
    const int llo = lane & 15, lhi = lane >> 4;
    const int wr = w >> 2, wc = w & 3;

    const int nwg = gridDim.x;
    const int bid = blockIdx.x;
    const int swz = (bid & 7) * (nwg >> 3) + (bid >> 3);
    const int nby = M >> 8;
    const int by = swz % nby, bx = swz / nby;
    const int row0 = by * 256, col0 = bx * BN;

    const int cko0 = ((lhi) ^ (llo & 7)) * 16;
    const int cko1 = ((4 + lhi) ^ (llo & 7)) * 16;

    const int l3 = lane >> 3;
    const int klog8 = ((lane & 7) ^ l3) * 8;
    const int rA_base = ((w >> 1) & 3) * 16 + (w & 1) * 8 + l3;
    const int rB_ws = w * 8 + l3;

    const __hip_bfloat16* Asrc[2][2];
#pragma unroll
    for (int h = 0; h < 2; ++h)
#pragma unroll
        for (int s = 0; s < 2; ++s)
            Asrc[h][s] = A + (size_t)(row0 + s * 128 + h * 64 + rA_base) * K + klog8;
    const __hip_bfloat16* Bsrc[2][2];
#pragma unroll
    for (int h = 0; h < 2; ++h)
#pragma unroll
        for (int s = 0; s < 2; ++s)
            Bsrc[h][s] = Bt + (size_t)(col0 + h * (BN / 2) + (SB == 2 ? s * 64 : 0) + rB_ws) * K + klog8;

#define STAGE_A(bufv, hh, tt) do {                                                            \
    load_lds16(Asrc[hh][0] + (size_t)(tt) * 64, smem + (bufv) * BUF + (hh) * 16384 + w * 1024);        \
    load_lds16(Asrc[hh][1] + (size_t)(tt) * 64, smem + (bufv) * BUF + (hh) * 16384 + 8192 + w * 1024); \
} while (0)
#define STAGE_B(bufv, hh, tt) do {                                                                     \
    load_lds16(Bsrc[hh][0] + (size_t)(tt) * 64, smem + (bufv) * BUF + ABYT + (hh) * (BBYT / 2) + w * 1024); \
    if (SB == 2)                                                                                       \
        load_lds16(Bsrc[hh][1] + (size_t)(tt) * 64, smem + (bufv) * BUF + ABYT + (hh) * (BBYT / 2) + 8192 + w * 1024); \
} while (0)

    f32x4 acc[8][BNT] = {};
    const int NT = K >> 6;

    STAGE_B(0, 0, 0); STAGE_B(0, 1, 0); STAGE_A(0, 0, 0); STAGE_A(0, 1, 0);
    asm volatile("s_waitcnt vmcnt(0)");
    __builtin_amdgcn_s_barrier();

    short8v bfr[BNT][2];
    for (int t = 0; t < NT; ++t) {
        const int buf = t & 1;
        const bool more = (t + 1) < NT;
        char* const base = smem + buf * BUF;
#pragma unroll
        for (int ph = 0; ph < 4; ++ph) {
            if (ph == 0) {
#pragma unroll
                for (int n = 0; n < BNT; ++n) {
                    const int brow = wc * (BNT * 16) + n * 16 + llo;
                    bfr[n][0] = *(const short8v*)(base + ABYT + brow * 128 + cko0);
                    bfr[n][1] = *(const short8v*)(base + ABYT + brow * 128 + cko1);
                }
            }
            const int mf0 = ph * 2, mf1 = ph * 2 + 1;
            const int slot0 = (mf0 >> 2) * 128 + wr * 64 + (mf0 & 3) * 16 + llo;
            const int slot1 = (mf1 >> 2) * 128 + wr * 64 + (mf1 & 3) * 16 + llo;
            const short8v a0k0 = *(const short8v*)(base + slot0 * 128 + cko0);
            const short8v a0k1 = *(const short8v*)(base + slot0 * 128 + cko1);
            const short8v a1k0 = *(const short8v*)(base + slot1 * 128 + cko0);
            const short8v a1k1 = *(const short8v*)(base + slot1 * 128 + cko1);
            if (more) {
                if (ph == 0) { STAGE_B(buf ^ 1, 0, t + 1); STAGE_B(buf ^ 1, 1, t + 1); }
                else if (ph == 1) { STAGE_A(buf ^ 1, 0, t + 1); STAGE_A(buf ^ 1, 1, t + 1); }
            }
            __builtin_amdgcn_s_barrier();
            __builtin_amdgcn_s_setprio(1);
#pragma unroll
            for (int n = 0; n < BNT; ++n) {
                acc[mf0][n] = __builtin_amdgcn_mfma_f32_16x16x32_bf16(a0k0, bfr[n][0], acc[mf0][n], 0, 0, 0);
                acc[mf0][n] = __builtin_amdgcn_mfma_f32_16x16x32_bf16(a0k1, bfr[n][1], acc[mf0][n], 0, 0, 0);
                acc[mf1][n] = __builtin_amdgcn_mfma_f32_16x16x32_bf16(a1k0, bfr[n][0], acc[mf1][n], 0, 0, 0);
                acc[mf1][n] = __builtin_amdgcn_mfma_f32_16x16x32_bf16(a1k1, bfr[n][1], acc[mf1][n], 0, 0, 0);
            }
            __builtin_amdgcn_s_setprio(0);
            if (ph == 3) { asm volatile("s_waitcnt vmcnt(0)"); }
            __builtin_amdgcn_s_barrier();
        }
    }
#undef STAGE_A
#undef STAGE_B

    if (EPI == 3) {
#pragma unroll
        for (int n = 0; n < BNT; ++n) {
            const int col = col0 + wc * (BNT * 16) + n * 16 + llo;
            const int proj = col0 >> 10;
            const int lcol = col & 1023;
            const float bs = (proj == 0 ? bias : proj == 1 ? bias2 : bias3)[lcol];
#pragma unroll
            for (int mf = 0; mf < 8; ++mf) {
                const int rbase = row0 + wr * 128 + mf * 16 + lhi * 4;
                if (proj == 2) {
                    const int bb = rbase >> 9, srow = rbase & 511;
                    const int hh = lcol >> 6, dk = lcol & 63;
                    union { ushort4 u4; ushort u[4]; } pk;
#pragma unroll
                    for (int j = 0; j < 4; ++j) pk.u[j] = f2bf_raw(acc[mf][n][j] + bs);
                    *(ushort4*)&((ushort*)C3)[(((size_t)(bb * 16 + hh) * 64 + dk) << 9) + srow] = pk.u4;
                } else {
                    __hip_bfloat16* dst = proj == 0 ? (__hip_bfloat16*)C : (__hip_bfloat16*)C2;
                    const float sc = proj == 0 ? SCQ_ : 1.0f;
#pragma unroll
                    for (int j = 0; j < 4; ++j)
                        dst[(size_t)(rbase + j) * D_ + lcol] = __float2bfloat16((acc[mf][n][j] + bs) * sc);
                }
            }
        }
    } else {
        constexpr int WCOL = BNT * 16;
        constexpr int ESTR = WCOL + 4;
        float* const eslab = (float*)smem + w * (16 * ESTR);
        const int rr = lane >> 2;
        const int cq = lane & 3;
        const int c0 = cq * (BNT * 4);
        const int gcolb = col0 + wc * WCOL + c0;
#pragma unroll
        for (int mf = 0; mf < 8; ++mf) {
#pragma unroll
            for (int n = 0; n < BNT; ++n)
#pragma unroll
                for (int j = 0; j < 4; ++j)
                    eslab[(lhi * 4 + j) * ESTR + n * 16 + llo] = acc[mf][n][j];
            const int grow = row0 + wr * 128 + mf * 16 + rr;
            if (EPI == 1) {
                ushort tmp[BNT * 4];
#pragma unroll
                for (int i = 0; i < BNT; ++i) {
                    float4 v = *(float4*)&eslab[rr * ESTR + c0 + i * 4];
                    const float4 b4 = *(const float4*)&bias[gcolb + i * 4];
                    tmp[i * 4 + 0] = f2bf_raw(gelu_f(v.x + b4.x));
                    tmp[i * 4 + 1] = f2bf_raw(gelu_f(v.y + b4.y));
                    tmp[i * 4 + 2] = f2bf_raw(gelu_f(v.z + b4.z));
                    tmp[i * 4 + 3] = f2bf_raw(gelu_f(v.w + b4.w));
                }
                ushort* dst = (ushort*)C + (size_t)grow * N + gcolb;
#pragma unroll
                for (int i = 0; i < BNT / 2; ++i)
                    *(short8v*)(dst + i * 8) = *(short8v*)&tmp[i * 8];
            } else {
#pragma unroll
                for (int i = 0; i < BNT; ++i) {
                    float4 v = *(float4*)&eslab[rr * ESTR + c0 + i * 4];
                    const float4 b4 = *(const float4*)&bias[gcolb + i * 4];
                    const float4 r4 = *(const float4*)&res[(size_t)grow * N + gcolb + i * 4];
                    v.x += b4.x + r4.x;
                    v.y += b4.y + r4.y;
                    v.z += b4.z + r4.z;
                    v.w += b4.w + r4.w;
                    *(float4*)&((float*)C)[(size_t)grow * N + gcolb + i * 4] = v;
                }
            }
        }
    }
}

// ---------------------------------------------------------------------------
// MFMA flash attention (round-11 exact: KVBLK=64 + T13 defer-max).
// ---------------------------------------------------------------------------
__global__ __launch_bounds__(256) void attn_mfma_k(
    const __hip_bfloat16* __restrict__ q, const __hip_bfloat16* __restrict__ k,
    const __hip_bfloat16* __restrict__ vt, const unsigned long long* __restrict__ mbits,
    __hip_bfloat16* __restrict__ o)
{
    const int qt = blockIdx.x;
    const int bh = blockIdx.y;
    const int b = bh >> 4, h = bh & 15;

    __shared__ __align__(16) __hip_bfloat16 Qs[64 * 72];
    __shared__ __align__(16) __hip_bfloat16 Ks[64 * 72];
    __shared__ __align__(16) __hip_bfloat16 Vts[64 * 72];
    __shared__ __align__(16) __hip_bfloat16 Pt[64 * 72];

    const int tid = threadIdx.x;
    const int w = tid >> 6, l = tid & 63;
    const int llo = l & 15, lhi = l >> 4;
    const int srow = tid >> 2, schk = tid & 3;

    {
        const __hip_bfloat16* qg =
            q + (size_t)(b * S_ + qt * 64 + srow) * D_ + h * 64 + schk * 16;
        *(short8v*)&Qs[srow * 72 + schk * 16] = *(const short8v*)qg;
        *(short8v*)&Qs[srow * 72 + schk * 16 + 8] = *(const short8v*)(qg + 8);
    }

    const __hip_bfloat16* kptr = k + (size_t)(b * S_ + srow) * D_ + h * 64 + schk * 16;
    const __hip_bfloat16* vptr = vt + (((size_t)(b * 16 + h) * 64 + srow) << 9) + schk * 16;
    short8v kr0 = *(const short8v*)kptr;
    short8v kr1 = *(const short8v*)(kptr + 8);
    short8v vr0 = *(const short8v*)vptr;
    short8v vr1 = *(const short8v*)(vptr + 8);

    __syncthreads();

    const short8v qa0 = *(const short8v*)&Qs[(w * 16 + llo) * 72 + lhi * 8];
    const short8v qa1 = *(const short8v*)&Qs[(w * 16 + llo) * 72 + 32 + lhi * 8];

    const unsigned long long* mrow =
        mbits + (((size_t)(b * S_ + qt * 64 + w * 16 + lhi * 4)) << 3);

    f32x4 oacc[4] = {};
    float m_r[4] = {-INFINITY, -INFINITY, -INFINITY, -INFINITY};
    float l_r[4] = {0.f, 0.f, 0.f, 0.f};

    for (int kt = 0; kt < 8; ++kt) {
        *(short8v*)&Ks[srow * 72 + schk * 16] = kr0;
        *(short8v*)&Ks[srow * 72 + schk * 16 + 8] = kr1;
        *(short8v*)&Vts[srow * 72 + schk * 16] = vr0;
        *(short8v*)&Vts[srow * 72 + schk * 16 + 8] = vr1;
        __syncthreads();

        short8v nk0, nk1, nv0, nv1;
        if (kt < 7) {
            const __hip_bfloat16* kp = kptr + (size_t)(kt + 1) * (64 * D_);
            const __hip_bfloat16* vp = vptr + (kt + 1) * 64;
            nk0 = *(const short8v*)kp;
            nk1 = *(const short8v*)(kp + 8);
            nv0 = *(const short8v*)vp;
            nv1 = *(const short8v*)(vp + 8);
        }

        f32x4 sacc[4] = {};
#pragma unroll
        for (int n = 0; n < 4; ++n)
            sacc[n] = __builtin_amdgcn_mfma_f32_16x16x32_bf16(
                qa0, *(const short8v*)&Ks[(n * 16 + llo) * 72 + lhi * 8], sacc[n], 0, 0, 0);
#pragma unroll
        for (int n = 0; n < 4; ++n)
            sacc[n] = __builtin_amdgcn_mfma_f32_16x16x32_bf16(
                qa1, *(const short8v*)&Ks[(n * 16 + llo) * 72 + 32 + lhi * 8], sacc[n], 0, 0, 0);

#pragma unroll
        for (int j = 0; j < 4; ++j) {
            const unsigned long long mb = mrow[j * 8 + kt];
            const float s0 = ((mb >> llo) & 1ull)        ? sacc[0][j] : NEG_;
            const float s1 = ((mb >> (llo + 16)) & 1ull) ? sacc[1][j] : NEG_;
            const float s2 = ((mb >> (llo + 32)) & 1ull) ? sacc[2][j] : NEG_;
            const float s3 = ((mb >> (llo + 48)) & 1ull) ? sacc[3][j] : NEG_;
            float pm = fmaxf(fmaxf(s0, s1), fmaxf(s2, s3));
            pm = fmaxf(pm, __shfl_xor(pm, 1));
            pm = fmaxf(pm, __shfl_xor(pm, 2));
            pm = fmaxf(pm, __shfl_xor(pm, 4));
            pm = fmaxf(pm, __shfl_xor(pm, 8));
            float alpha = 1.0f;
            if (!__all(pm <= m_r[j] + 8.0f)) {
                const float mnew = fmaxf(m_r[j], pm);
                alpha = exp2f(m_r[j] - mnew);
                m_r[j] = mnew;
#pragma unroll
                for (int df = 0; df < 4; ++df) oacc[df][j] *= alpha;
            }
            const float p0 = exp2f(s0 - m_r[j]);
            const float p1 = exp2f(s1 - m_r[j]);
            const float p2 = exp2f(s2 - m_r[j]);
            const float p3 = exp2f(s3 - m_r[j]);
            float rsum = p0 + p1 + p2 + p3;
            rsum += __shfl_xor(rsum, 1);
            rsum += __shfl_xor(rsum, 2);
            rsum += __shfl_xor(rsum, 4);
            rsum += __shfl_xor(rsum, 8);
            l_r[j] = l_r[j] * alpha + rsum;
            const int prow = (w * 16 + lhi * 4 + j) * 72;
            Pt[prow + llo]      = __float2bfloat16(p0);
            Pt[prow + llo + 16] = __float2bfloat16(p1);
            Pt[prow + llo + 32] = __float2bfloat16(p2);
            Pt[prow + llo + 48] = __float2bfloat16(p3);
        }

#pragma unroll
        for (int ks = 0; ks < 2; ++ks) {
            const short8v pa = *(const short8v*)&Pt[(w * 16 + llo) * 72 + ks * 32 + lhi * 8];
#pragma unroll
            for (int df = 0; df < 4; ++df) {
                const short8v vb = *(const short8v*)&Vts[(df * 16 + llo) * 72 + ks * 32 + lhi * 8];
                oacc[df] = __builtin_amdgcn_mfma_f32_16x16x32_bf16(pa, vb, oacc[df], 0, 0, 0);
            }
        }
        __syncthreads();

        if (kt < 7) { kr0 = nk0; kr1 = nk1; vr0 = nv0; vr1 = nv1; }
    }

#pragma unroll
    for (int j = 0; j < 4; ++j) {
        const float inv = 1.0f / l_r[j];
        __hip_bfloat16* orow =
            o + (size_t)(b * S_ + qt * 64 + w * 16 + lhi * 4 + j) * D_ + h * 64;
#pragma unroll
        for (int df = 0; df < 4; ++df)
            orow[df * 16 + llo] = __float2bfloat16(oacc[df][j] * inv);
    }
}

// ---------------------------------------------------------------------------
// launch (10 dispatches)
// ---------------------------------------------------------------------------
extern "C" void kernel_launch(void* const* d_in, const int* in_sizes, int n_in,
                              void* d_out, int out_size, void* d_ws, size_t ws_size,
                              hipStream_t stream)
{
    const float* x    = (const float*)d_in[0];
    const int*   mask = (const int*)d_in[1];
    const float* wq   = (const float*)d_in[2];
    const float* bq   = (const float*)d_in[3];
    const float* wk   = (const float*)d_in[4];
    const float* bk   = (const float*)d_in[5];
    const float* wv   = (const float*)d_in[6];
    const float* bv   = (const float*)d_in[7];
    const float* wo   = (const float*)d_in[8];
    const float* bo   = (const float*)d_in[9];
    const float* w1   = (const float*)d_in[10];
    const float* b1   = (const float*)d_in[11];
    const float* w2   = (const float*)d_in[12];
    const float* b2   = (const float*)d_in[13];
    const float* ln1g = (const float*)d_in[14];
    const float* ln1b = (const float*)d_in[15];
    const float* ln2g = (const float*)d_in[16];
    const float* ln2b = (const float*)d_in[17];
    float* out = (float*)d_out;
    char* ws = (char*)d_ws;

    const size_t MB = 1024 * 1024;
    __hip_bfloat16* hb    = (__hip_bfloat16*)(ws);
    __hip_bfloat16* qbh   = (__hip_bfloat16*)(ws + 16 * MB);
    __hip_bfloat16* kbh   = (__hip_bfloat16*)(ws + 32 * MB);
    __hip_bfloat16* vth   = (__hip_bfloat16*)(ws + 48 * MB);
    __hip_bfloat16* attnb = (__hip_bfloat16*)(ws + 64 * MB);
    __hip_bfloat16* ff1b  = (__hip_bfloat16*)(ws + 16 * MB);
    __hip_bfloat16* wcat  = (__hip_bfloat16*)(ws + 80 * MB);
    __hip_bfloat16* wot   = (__hip_bfloat16*)(ws + 86 * MB);
    __hip_bfloat16* w1t   = (__hip_bfloat16*)(ws + 88 * MB);
    __hip_bfloat16* w2t   = (__hip_bfloat16*)(ws + 96 * MB);
    unsigned int*   scales = (unsigned int*)(ws + 104 * MB);
    unsigned long long* mbits = (unsigned long long*)(ws + 105 * MB);

    maskpack_k<<<(B_ * S_ * (S_ / 64)) / 4, 256, 0, stream>>>(mask, mbits, scales);
    maxabs3_k<<<dim3(256, 3), 256, 0, stream>>>(wq, wk, wv, scales, D_ * D_);
    transq_all_k<<<12288, dim3(32, 8), 0, stream>>>(
        wq, wk, wv, wo, w1, w2, scales, wcat, wot, w1t, w2t);

    ln_bf16_k<<<NROW, 256, 0, stream>>>(x, ln1g, ln1b, hb);

    // fused QKV: N = 3072, BNT=4  -> grid 384
    gemm256<4, 3><<<(3 * D_ / 256) * (NROW / 256), 512, 0, stream>>>(
        hb, wcat, bq, bk, bv, nullptr, qbh, kbh, vth, NROW, 3 * D_, D_);

    attn_mfma_k<<<dim3(S_ / 64, B_ * H_), 256, 0, stream>>>(qbh, kbh, vth, mbits, attnb);

    // x2 = x + attn @ wo + bo -> out (fp32).  BNT=2 -> grid 256
    gemm256<2, 2><<<(D_ / 128) * (NROW / 256), 512, 0, stream>>>(
        attnb, wot, bo, nullptr, nullptr, x, out, nullptr, nullptr, NROW, D_, D_);

    ln_bf16_k<<<NROW, 256, 0, stream>>>(out, ln2g, ln2b, hb);

    // ff1 = gelu(h2 @ w1 + b1) -> bf16.  BNT=4 -> grid 512
    gemm256<4, 1><<<(DFF_ / 256) * (NROW / 256), 512, 0, stream>>>(
        hb, w1t, b1, nullptr, nullptr, nullptr, ff1b, nullptr, nullptr, NROW, DFF_, D_);

    // out = x2 + ff1 @ w2 + b2 (fp32, res==C aliasing is per-thread-safe)
    gemm256<2, 2><<<(D_ / 128) * (NROW / 256), 512, 0, stream>>>(
        ff1b, w2t, b2, nullptr, nullptr, out, out, nullptr, nullptr, NROW, D_, DFF_);
}